// Round 11
// baseline (249.991 us; speedup 1.0000x reference)
//
#include <hip/hip_runtime.h>
#include <hip/hip_bf16.h>
#include <stdint.h>

#define B_ROWS 4096
#define D_K    256
#define Q_ROWS 65536
#define HALF   2048

typedef __bf16 bf16x8 __attribute__((ext_vector_type(8)));
typedef float  f32x4  __attribute__((ext_vector_type(4)));
typedef int    v8i    __attribute__((ext_vector_type(8)));
typedef int    v4i    __attribute__((ext_vector_type(4)));
typedef unsigned short u16x8 __attribute__((ext_vector_type(8)));
typedef const __attribute__((address_space(1))) void* gptr1;
typedef __attribute__((address_space(3))) void* lptr3;

__device__ __forceinline__ unsigned int f32_ordered(float f) {
    unsigned int u = __float_as_uint(f);
    return (u & 0x80000000u) ? ~u : (u | 0x80000000u);
}

__device__ __forceinline__ unsigned short f2bf_rn(float f) {
    unsigned int u = __float_as_uint(f);
    u += 0x7FFFu + ((u >> 16) & 1u);
    return (unsigned short)(u >> 16);
}

// ---------- fused prep: emb/queue -> fp8 e4m3, preds -> bf16, zero amax/out ----------
#define EMB4  (B_ROWS * D_K / 4)          // 262144
#define PRED4 (B_ROWS * D_K / 4)          // 262144
#define QUE4  (Q_ROWS * D_K / 4)          // 4194304
__global__ __launch_bounds__(256) void prep_kernel(const float* __restrict__ emb,
                                                   const float* __restrict__ preds,
                                                   const float* __restrict__ queue,
                                                   unsigned char* __restrict__ emb8,
                                                   unsigned short* __restrict__ preds_bf,
                                                   unsigned char* __restrict__ queue8,
                                                   unsigned long long* __restrict__ amax,
                                                   float* __restrict__ out) {
    int i = blockIdx.x * 256 + threadIdx.x;
    if (i < EMB4) {
        float4 v = ((const float4*)emb)[i];
        int u = __builtin_amdgcn_cvt_pk_fp8_f32(v.x, v.y, 0, false);
        u     = __builtin_amdgcn_cvt_pk_fp8_f32(v.z, v.w, u, true);
        ((int*)emb8)[i] = u;
    } else if (i < EMB4 + PRED4) {
        int off = i - EMB4;
        float4 v = ((const float4*)preds)[off];
        ushort4 o;
        o.x = f2bf_rn(v.x); o.y = f2bf_rn(v.y); o.z = f2bf_rn(v.z); o.w = f2bf_rn(v.w);
        ((ushort4*)preds_bf)[off] = o;
    } else {
        int off = i - EMB4 - PRED4;
        float4 v = ((const float4*)queue)[off];
        int u = __builtin_amdgcn_cvt_pk_fp8_f32(v.x, v.y, 0, false);
        u     = __builtin_amdgcn_cvt_pk_fp8_f32(v.z, v.w, u, true);
        ((int*)queue8)[off] = u;
    }
    if (i < B_ROWS) amax[i] = 0ull;   // ordered-float 0 == below every real value
    if (i == 0) out[0] = 0.f;
}

// ---------- fused sim GEMM + row argmax, MX-fp8 (scale=1.0) ----------
// A fragments are block-lifetime constants: staged to LDS once, read to 64
// VGPRs, then the SAME 32 KB LDS is reused as the B double-buffer. K-loop has
// B-only staging + B-only ds_reads; launch_bounds(256,3) -> 3 blocks/CU.
#define BM 128
#define BN 128
#define NCHUNK 8
#define MFMA_FP8(av, bv, c) \
    __builtin_amdgcn_mfma_scale_f32_16x16x128_f8f6f4((av), (bv), (c), 0, 0, 0, 0x7F7F7F7F, 0, 0x7F7F7F7F)

__global__ __launch_bounds__(256, 3) void sim_argmax_kernel(const unsigned char* __restrict__ A8,
                                                            const unsigned char* __restrict__ B8,
                                                            unsigned long long* __restrict__ amax) {
    __shared__ unsigned char sh[32768];   // phase 1: A tile; phase 2: B dbuf (2 x 16 KB)

    const int tid  = threadIdx.x;
    const int wave = tid >> 6;          // 0..3
    const int lane = tid & 63;
    const int l15  = lane & 15;
    const int quad = lane >> 4;

    // XCD-aware swizzle: block i -> XCD i%8 (dispatch heuristic).
    const int bid  = blockIdx.x;
    const int xcd  = bid & 7;
    const int j    = bid >> 3;
    const int blk_m = (j & 31) * BM;
    const int ngrp  = (j >> 5) * 8 + xcd;
    const int nbase = ngrp * (BN * NCHUNK);

    const int wave_m = (wave >> 1) * 64;
    const int wave_n = (wave & 1) * 64;

    // ---- phase 1: stage A (32 KB) into sh, swizzled: LDS byte j*4096 + tid*16
    // holds row r = j*16 + (tid>>4), slot tid&15; global granule g = slot ^ (r&15).
    {
        const unsigned char* gA = A8 + (size_t)(blk_m + (tid >> 4)) * D_K
                                     + (((tid & 15) ^ ((tid >> 4) & 15)) << 4);
#pragma unroll
        for (int jj = 0; jj < 8; jj++)
            __builtin_amdgcn_global_load_lds((gptr1)(gA + jj * 4096),
                                             (lptr3)&sh[jj * 4096 + wave * 1024], 16, 0, 0);
    }
    __syncthreads();   // A resident in LDS

    // read A fragments into registers: areg[kt][mi], 8 x v8i = 64 VGPRs
    const int pA = (quad * 2) ^ l15;          // slot of A lo-granule for kt=0
    v8i areg[2][4];
#pragma unroll
    for (int kt = 0; kt < 2; kt++) {
#pragma unroll
        for (int mi = 0; mi < 4; mi++) {
            const int _lo = (wave_m + mi * 16 + l15) * 256 + ((pA ^ (kt << 3)) << 4);
            v4i _x = *(const v4i*)&sh[_lo];
            v4i _y = *(const v4i*)&sh[_lo ^ 16];
            areg[kt][mi] = __builtin_shufflevector(_x, _y, 0, 1, 2, 3, 4, 5, 6, 7);
        }
    }
    __syncthreads();   // all lanes done reading A; sh becomes the B dbuf

    // ---- B staging base: issue j covers rows j*32 + (tid>>3), slot tid&7,
    // global granule g = slot ^ (r&7). Tile T: +(T>>1)*32768 + (T&1)*128 bytes.
    const unsigned char* gB = B8 + (size_t)(nbase + (tid >> 3)) * D_K
                                 + (((tid & 7) ^ ((tid >> 3) & 7)) << 4);

#define PREFB(T, BSOFF) do {                                                           \
        const int _off = ((T) >> 1) * (32 * D_K * 4) + ((T) & 1) * 128;                \
        _Pragma("unroll")                                                              \
        for (int _j = 0; _j < 4; _j++)                                                 \
            __builtin_amdgcn_global_load_lds((gptr1)(gB + _j * 8192 + _off),           \
                                             (lptr3)&sh[(BSOFF) + _j * 4096 + wave * 1024], 16, 0, 0); \
    } while (0)

    int Bbase[4];
#pragma unroll
    for (int ni = 0; ni < 4; ni++) Bbase[ni] = (wave_n + ni * 16 + l15) * 128;
    const int pB = (quad * 2) ^ (l15 & 7);    // slot of B lo-granule

    float bestv[4][4];
    int   bestc[4][4];
#pragma unroll
    for (int mi = 0; mi < 4; mi++)
#pragma unroll
        for (int reg = 0; reg < 4; reg++) { bestv[mi][reg] = -1e30f; bestc[mi][reg] = 0; }

    f32x4 acc[4][4];
#pragma unroll
    for (int i = 0; i < 4; i++)
#pragma unroll
        for (int jj = 0; jj < 4; jj++) acc[i][jj] = (f32x4){0.f, 0.f, 0.f, 0.f};

#define COMPUTE(BSOFF, KT) do {                                                        \
        _Pragma("unroll")                                                              \
        for (int ni = 0; ni < 4; ni++) {                                               \
            const int _lo = (BSOFF) + Bbase[ni] + (pB << 4);                           \
            v4i _x = *(const v4i*)&sh[_lo];                                            \
            v4i _y = *(const v4i*)&sh[_lo ^ 16];                                       \
            v8i bv = __builtin_shufflevector(_x, _y, 0, 1, 2, 3, 4, 5, 6, 7);          \
            _Pragma("unroll")                                                          \
            for (int mi = 0; mi < 4; mi++)                                             \
                acc[mi][ni] = MFMA_FP8(areg[KT][mi], bv, acc[mi][ni]);                 \
        }                                                                              \
    } while (0)

    PREFB(0, 0);   // prologue: B tile 0 -> buf0

#pragma unroll 1
    for (int p = 0; p < NCHUNK; ++p) {
        __syncthreads();                 // B tile 2p ready in buf0; buf1 free
        PREFB(2 * p + 1, 16384);
        COMPUTE(0, 0);                   // chunk p, k 0..127
        __syncthreads();                 // B tile 2p+1 ready in buf1; buf0 free
        if (p < NCHUNK - 1) PREFB(2 * p + 2, 0);
        COMPUTE(16384, 1);               // chunk p, k 128..255

        // chunk p complete: fold into running best, reset acc
        const int col0 = nbase + p * BN + wave_n + l15;
#pragma unroll
        for (int mi = 0; mi < 4; mi++) {
#pragma unroll
            for (int reg = 0; reg < 4; reg++) {
#pragma unroll
                for (int ni = 0; ni < 4; ni++) {
                    float v = acc[mi][ni][reg];
                    int   c = col0 + ni * 16;
                    if (v > bestv[mi][reg]) { bestv[mi][reg] = v; bestc[mi][reg] = c; }
                }
                acc[mi][0][reg] = 0.f; acc[mi][1][reg] = 0.f;
                acc[mi][2][reg] = 0.f; acc[mi][3][reg] = 0.f;
            }
        }
    }

    // Epilogue (once per block): pack, 16-lane reduce, one atomic per slot
#pragma unroll
    for (int mi = 0; mi < 4; mi++) {
#pragma unroll
        for (int reg = 0; reg < 4; reg++) {
            unsigned long long key =
                ((unsigned long long)f32_ordered(bestv[mi][reg]) << 32) |
                (unsigned long long)(0xFFFFFFFFu - (unsigned)bestc[mi][reg]);   // ~col: ties -> smaller col
#pragma unroll
            for (int m = 1; m < 16; m <<= 1) {
                unsigned long long o = __shfl_xor(key, m, 16);
                if (o > key) key = o;
            }
            if (l15 == mi * 4 + reg) {
                int row = blk_m + wave_m + mi * 16 + quad * 4 + reg;
                atomicMax(&amax[row], key);
            }
        }
    }
}

// ---------- logits + online logsumexp - diag + final reduce ---------- (R8 body)
// Gather reads the ORIGINAL fp32 queue (full precision), converts to bf16
// fragments in-register. One block (8 waves) per 16 rows; waves split the
// 128 column-tiles 16 each; merged through LDS; one atomicAdd per block.
__global__ __launch_bounds__(512) void logits_ce_kernel(const unsigned long long* __restrict__ amax,
                                                        const float* __restrict__ queue_f32,
                                                        const unsigned short* __restrict__ preds_bf,
                                                        float* __restrict__ out) {
    const int gw   = blockIdx.x;        // 0..255 (16-row group)
    const int tid  = threadIdx.x;
    const int wave = tid >> 6;          // 0..7
    const int lane = tid & 63;
    const int l15  = lane & 15;
    const int quad = lane >> 4;
    const int h    = gw >> 7;           // 0: ab, 1: ba
    const int rowbase = gw * 16;
    const unsigned short* Bbase = preds_bf + (size_t)((1 - h) * HALF) * D_K;

    __shared__ float sm[8][16], sl[8][16], sd[8][16];

    // inline gather from fp32 queue: this lane's A-row = queue[argmax(rowbase+l15)]
    unsigned idx = 0xFFFFFFFFu - (unsigned)(amax[rowbase + l15] & 0xFFFFFFFFull);
    const float* arow = queue_f32 + (size_t)idx * D_K;
    bf16x8 a[8];
#pragma unroll
    for (int kc = 0; kc < 8; kc++) {
        float4 f0 = *(const float4*)(arow + kc * 32 + quad * 8);
        float4 f1 = *(const float4*)(arow + kc * 32 + quad * 8 + 4);
        u16x8 t;
        t[0] = f2bf_rn(f0.x); t[1] = f2bf_rn(f0.y); t[2] = f2bf_rn(f0.z); t[3] = f2bf_rn(f0.w);
        t[4] = f2bf_rn(f1.x); t[5] = f2bf_rn(f1.y); t[6] = f2bf_rn(f1.z); t[7] = f2bf_rn(f1.w);
        a[kc] = *(const bf16x8*)&t;
    }

    float m_run[4], l_run[4], diag[4];
#pragma unroll
    for (int r = 0; r < 4; r++) { m_run[r] = -1e30f; l_run[r] = 0.f; diag[r] = -1e30f; }

    const int tdiag = gw & 127;
    for (int tt = 0; tt < 16; tt++) {
        const int t = wave * 16 + tt;
        f32x4 acc = (f32x4){0.f, 0.f, 0.f, 0.f};
#pragma unroll
        for (int kc = 0; kc < 8; kc++) {
            bf16x8 b = *(const bf16x8*)&Bbase[(size_t)(t * 16 + l15) * D_K + kc * 32 + quad * 8];
            acc = __builtin_amdgcn_mfma_f32_16x16x32_bf16(a[kc], b, acc, 0, 0, 0);
        }
#pragma unroll
        for (int reg = 0; reg < 4; reg++) {
            float v = acc[reg] * 10.0f;              // 1/TEMPERATURE
            if (t == tdiag && l15 == quad * 4 + reg) diag[reg] = v;
            float nm = fmaxf(m_run[reg], v);
            l_run[reg] = l_run[reg] * __expf(m_run[reg] - nm) + __expf(v - nm);
            m_run[reg] = nm;
        }
    }
    // 16-lane merge within the wave
#pragma unroll
    for (int reg = 0; reg < 4; reg++) {
#pragma unroll
        for (int m = 1; m < 16; m <<= 1) {
            float om = __shfl_xor(m_run[reg], m, 16);
            float ol = __shfl_xor(l_run[reg], m, 16);
            float od = __shfl_xor(diag[reg], m, 16);
            float nm = fmaxf(m_run[reg], om);
            l_run[reg] = l_run[reg] * __expf(m_run[reg] - nm) + ol * __expf(om - nm);
            m_run[reg] = nm;
            diag[reg] = fmaxf(diag[reg], od);
        }
        if (l15 == 0) {
            sm[wave][quad * 4 + reg] = m_run[reg];
            sl[wave][quad * 4 + reg] = l_run[reg];
            sd[wave][quad * 4 + reg] = diag[reg];
        }
    }
    __syncthreads();
    // cross-wave merge + block-local reduce + single atomic into out
    if (tid < 16) {
        float M = -1e30f, L = 0.f, Dg = -1e30f;
#pragma unroll
        for (int w = 0; w < 8; w++) {
            float mw = sm[w][tid], lw = sl[w][tid], dw = sd[w][tid];
            float nM = fmaxf(M, mw);
            L = L * __expf(M - nM) + lw * __expf(mw - nM);
            M = nM;
            Dg = fmaxf(Dg, dw);
        }
        float rl = (M + __logf(L)) - Dg;
#pragma unroll
        for (int m = 1; m < 16; m <<= 1) rl += __shfl_xor(rl, m, 16);
        if (tid == 0) atomicAdd(out, rl * (1.0f / (float)B_ROWS));
    }
}

extern "C" void kernel_launch(void* const* d_in, const int* in_sizes, int n_in,
                              void* d_out, int out_size, void* d_ws, size_t ws_size,
                              hipStream_t stream) {
    const float* emb   = (const float*)d_in[0];
    const float* preds = (const float*)d_in[1];
    const float* queue = (const float*)d_in[2];

    char* w = (char*)d_ws;
    unsigned long long* amax  = (unsigned long long*)w;                     // 32 KB
    unsigned char*  emb8      = (unsigned char*)(w + (1u << 20));           // 1 MB
    unsigned short* preds_bf  = (unsigned short*)(w + (2u << 20));          // 2 MB
    unsigned char*  queue8    = (unsigned char*)(w + (4u << 20));           // 16 MB

    prep_kernel<<<dim3((EMB4 + PRED4 + QUE4) / 256), 256, 0, stream>>>(
        emb, preds, queue, emb8, preds_bf, queue8, amax, (float*)d_out);
    sim_argmax_kernel<<<dim3((B_ROWS / BM) * (Q_ROWS / (BN * NCHUNK))), 256, 0, stream>>>(
        emb8, queue8, amax);
    logits_ce_kernel<<<dim3(B_ROWS / 16), 512, 0, stream>>>(
        amax, queue, preds_bf, (float*)d_out);
}

// Round 12
// 213.146 us; speedup vs baseline: 1.1729x; 1.1729x over previous
//
#include <hip/hip_runtime.h>
#include <hip/hip_bf16.h>
#include <stdint.h>

#define B_ROWS 4096
#define D_K    256
#define Q_ROWS 65536
#define HALF   2048

typedef __bf16 bf16x8 __attribute__((ext_vector_type(8)));
typedef float  f32x4  __attribute__((ext_vector_type(4)));
typedef int    v8i    __attribute__((ext_vector_type(8)));
typedef int    v4i    __attribute__((ext_vector_type(4)));
typedef unsigned short u16x8 __attribute__((ext_vector_type(8)));
typedef const __attribute__((address_space(1))) void* gptr1;
typedef __attribute__((address_space(3))) void* lptr3;

__device__ __forceinline__ unsigned int f32_ordered(float f) {
    unsigned int u = __float_as_uint(f);
    return (u & 0x80000000u) ? ~u : (u | 0x80000000u);
}

__device__ __forceinline__ unsigned short f2bf_rn(float f) {
    unsigned int u = __float_as_uint(f);
    u += 0x7FFFu + ((u >> 16) & 1u);
    return (unsigned short)(u >> 16);
}

// ---------- fused prep: emb/queue -> fp8 e4m3, preds -> bf16, zero amax/out ----------
#define EMB4  (B_ROWS * D_K / 4)          // 262144
#define PRED4 (B_ROWS * D_K / 4)          // 262144
#define QUE4  (Q_ROWS * D_K / 4)          // 4194304
__global__ __launch_bounds__(256) void prep_kernel(const float* __restrict__ emb,
                                                   const float* __restrict__ preds,
                                                   const float* __restrict__ queue,
                                                   unsigned char* __restrict__ emb8,
                                                   unsigned short* __restrict__ preds_bf,
                                                   unsigned char* __restrict__ queue8,
                                                   unsigned long long* __restrict__ amax,
                                                   float* __restrict__ out) {
    int i = blockIdx.x * 256 + threadIdx.x;
    if (i < EMB4) {
        float4 v = ((const float4*)emb)[i];
        int u = __builtin_amdgcn_cvt_pk_fp8_f32(v.x, v.y, 0, false);
        u     = __builtin_amdgcn_cvt_pk_fp8_f32(v.z, v.w, u, true);
        ((int*)emb8)[i] = u;
    } else if (i < EMB4 + PRED4) {
        int off = i - EMB4;
        float4 v = ((const float4*)preds)[off];
        ushort4 o;
        o.x = f2bf_rn(v.x); o.y = f2bf_rn(v.y); o.z = f2bf_rn(v.z); o.w = f2bf_rn(v.w);
        ((ushort4*)preds_bf)[off] = o;
    } else {
        int off = i - EMB4 - PRED4;
        float4 v = ((const float4*)queue)[off];
        int u = __builtin_amdgcn_cvt_pk_fp8_f32(v.x, v.y, 0, false);
        u     = __builtin_amdgcn_cvt_pk_fp8_f32(v.z, v.w, u, true);
        ((int*)queue8)[off] = u;
    }
    if (i < B_ROWS) amax[i] = 0ull;   // ordered-float 0 == below every real value
    if (i == 0) out[0] = 0.f;
}

// ---------- fused sim GEMM + row argmax, MX-fp8 (scale=1.0) ----------
// A fragments are block-lifetime constants: staged to LDS once, read to 64
// VGPRs, then the SAME 32 KB LDS is reused as the B double-buffer. K-loop has
// B-only staging + B-only ds_reads. launch_bounds(256,2): VGPR cap 256 so the
// 64-VGPR areg does NOT spill (R11's (256,3) cap ~170 spilled it: VGPR=84,
// WRITE_SIZE 55 MB of scratch traffic).
#define BM 128
#define BN 128
#define NCHUNK 8
#define MFMA_FP8(av, bv, c) \
    __builtin_amdgcn_mfma_scale_f32_16x16x128_f8f6f4((av), (bv), (c), 0, 0, 0, 0x7F7F7F7F, 0, 0x7F7F7F7F)

__global__ __launch_bounds__(256, 2) void sim_argmax_kernel(const unsigned char* __restrict__ A8,
                                                            const unsigned char* __restrict__ B8,
                                                            unsigned long long* __restrict__ amax) {
    __shared__ unsigned char sh[32768];   // phase 1: A tile; phase 2: B dbuf (2 x 16 KB)

    const int tid  = threadIdx.x;
    const int wave = tid >> 6;          // 0..3
    const int lane = tid & 63;
    const int l15  = lane & 15;
    const int quad = lane >> 4;

    // XCD-aware swizzle: block i -> XCD i%8 (dispatch heuristic).
    const int bid  = blockIdx.x;
    const int xcd  = bid & 7;
    const int j    = bid >> 3;
    const int blk_m = (j & 31) * BM;
    const int ngrp  = (j >> 5) * 8 + xcd;
    const int nbase = ngrp * (BN * NCHUNK);

    const int wave_m = (wave >> 1) * 64;
    const int wave_n = (wave & 1) * 64;

    // ---- phase 1: stage A (32 KB) into sh, swizzled: LDS byte j*4096 + tid*16
    // holds row r = j*16 + (tid>>4), slot tid&15; global granule g = slot ^ (r&15).
    {
        const unsigned char* gA = A8 + (size_t)(blk_m + (tid >> 4)) * D_K
                                     + (((tid & 15) ^ ((tid >> 4) & 15)) << 4);
#pragma unroll
        for (int jj = 0; jj < 8; jj++)
            __builtin_amdgcn_global_load_lds((gptr1)(gA + jj * 4096),
                                             (lptr3)&sh[jj * 4096 + wave * 1024], 16, 0, 0);
    }
    __syncthreads();   // A resident in LDS

    // read A fragments into registers: areg[kt][mi], 8 x v8i = 64 VGPRs
    const int pA = (quad * 2) ^ l15;          // slot of A lo-granule for kt=0
    v8i areg[2][4];
#pragma unroll
    for (int kt = 0; kt < 2; kt++) {
#pragma unroll
        for (int mi = 0; mi < 4; mi++) {
            const int _lo = (wave_m + mi * 16 + l15) * 256 + ((pA ^ (kt << 3)) << 4);
            v4i _x = *(const v4i*)&sh[_lo];
            v4i _y = *(const v4i*)&sh[_lo ^ 16];
            areg[kt][mi] = __builtin_shufflevector(_x, _y, 0, 1, 2, 3, 4, 5, 6, 7);
        }
    }
    __syncthreads();   // all lanes done reading A; sh becomes the B dbuf

    // ---- B staging base: issue j covers rows j*32 + (tid>>3), slot tid&7,
    // global granule g = slot ^ (r&7). Tile T: +(T>>1)*32768 + (T&1)*128 bytes.
    const unsigned char* gB = B8 + (size_t)(nbase + (tid >> 3)) * D_K
                                 + (((tid & 7) ^ ((tid >> 3) & 7)) << 4);

#define PREFB(T, BSOFF) do {                                                           \
        const int _off = ((T) >> 1) * (32 * D_K * 4) + ((T) & 1) * 128;                \
        _Pragma("unroll")                                                              \
        for (int _j = 0; _j < 4; _j++)                                                 \
            __builtin_amdgcn_global_load_lds((gptr1)(gB + _j * 8192 + _off),           \
                                             (lptr3)&sh[(BSOFF) + _j * 4096 + wave * 1024], 16, 0, 0); \
    } while (0)

    int Bbase[4];
#pragma unroll
    for (int ni = 0; ni < 4; ni++) Bbase[ni] = (wave_n + ni * 16 + l15) * 128;
    const int pB = (quad * 2) ^ (l15 & 7);    // slot of B lo-granule

    float bestv[4][4];
    int   bestc[4][4];
#pragma unroll
    for (int mi = 0; mi < 4; mi++)
#pragma unroll
        for (int reg = 0; reg < 4; reg++) { bestv[mi][reg] = -1e30f; bestc[mi][reg] = 0; }

    f32x4 acc[4][4];
#pragma unroll
    for (int i = 0; i < 4; i++)
#pragma unroll
        for (int jj = 0; jj < 4; jj++) acc[i][jj] = (f32x4){0.f, 0.f, 0.f, 0.f};

#define COMPUTE(BSOFF, KT) do {                                                        \
        _Pragma("unroll")                                                              \
        for (int ni = 0; ni < 4; ni++) {                                               \
            const int _lo = (BSOFF) + Bbase[ni] + (pB << 4);                           \
            v4i _x = *(const v4i*)&sh[_lo];                                            \
            v4i _y = *(const v4i*)&sh[_lo ^ 16];                                       \
            v8i bv = __builtin_shufflevector(_x, _y, 0, 1, 2, 3, 4, 5, 6, 7);          \
            _Pragma("unroll")                                                          \
            for (int mi = 0; mi < 4; mi++)                                             \
                acc[mi][ni] = MFMA_FP8(areg[KT][mi], bv, acc[mi][ni]);                 \
        }                                                                              \
    } while (0)

    PREFB(0, 0);   // prologue: B tile 0 -> buf0

#pragma unroll 1
    for (int p = 0; p < NCHUNK; ++p) {
        __syncthreads();                 // B tile 2p ready in buf0; buf1 free
        PREFB(2 * p + 1, 16384);
        COMPUTE(0, 0);                   // chunk p, k 0..127
        __syncthreads();                 // B tile 2p+1 ready in buf1; buf0 free
        if (p < NCHUNK - 1) PREFB(2 * p + 2, 0);
        COMPUTE(16384, 1);               // chunk p, k 128..255

        // chunk p complete: fold into running best, reset acc
        const int col0 = nbase + p * BN + wave_n + l15;
#pragma unroll
        for (int mi = 0; mi < 4; mi++) {
#pragma unroll
            for (int reg = 0; reg < 4; reg++) {
#pragma unroll
                for (int ni = 0; ni < 4; ni++) {
                    float v = acc[mi][ni][reg];
                    int   c = col0 + ni * 16;
                    if (v > bestv[mi][reg]) { bestv[mi][reg] = v; bestc[mi][reg] = c; }
                }
                acc[mi][0][reg] = 0.f; acc[mi][1][reg] = 0.f;
                acc[mi][2][reg] = 0.f; acc[mi][3][reg] = 0.f;
            }
        }
    }

    // Epilogue (once per block): pack, 16-lane reduce, one atomic per slot
#pragma unroll
    for (int mi = 0; mi < 4; mi++) {
#pragma unroll
        for (int reg = 0; reg < 4; reg++) {
            unsigned long long key =
                ((unsigned long long)f32_ordered(bestv[mi][reg]) << 32) |
                (unsigned long long)(0xFFFFFFFFu - (unsigned)bestc[mi][reg]);   // ~col: ties -> smaller col
#pragma unroll
            for (int m = 1; m < 16; m <<= 1) {
                unsigned long long o = __shfl_xor(key, m, 16);
                if (o > key) key = o;
            }
            if (l15 == mi * 4 + reg) {
                int row = blk_m + wave_m + mi * 16 + quad * 4 + reg;
                atomicMax(&amax[row], key);
            }
        }
    }
}

// ---------- logits + online logsumexp - diag + final reduce ---------- (R8 body)
// Gather reads the ORIGINAL fp32 queue (full precision), converts to bf16
// fragments in-register. One block (8 waves) per 16 rows; waves split the
// 128 column-tiles 16 each; merged through LDS; one atomicAdd per block.
__global__ __launch_bounds__(512) void logits_ce_kernel(const unsigned long long* __restrict__ amax,
                                                        const float* __restrict__ queue_f32,
                                                        const unsigned short* __restrict__ preds_bf,
                                                        float* __restrict__ out) {
    const int gw   = blockIdx.x;        // 0..255 (16-row group)
    const int tid  = threadIdx.x;
    const int wave = tid >> 6;          // 0..7
    const int lane = tid & 63;
    const int l15  = lane & 15;
    const int quad = lane >> 4;
    const int h    = gw >> 7;           // 0: ab, 1: ba
    const int rowbase = gw * 16;
    const unsigned short* Bbase = preds_bf + (size_t)((1 - h) * HALF) * D_K;

    __shared__ float sm[8][16], sl[8][16], sd[8][16];

    // inline gather from fp32 queue: this lane's A-row = queue[argmax(rowbase+l15)]
    unsigned idx = 0xFFFFFFFFu - (unsigned)(amax[rowbase + l15] & 0xFFFFFFFFull);
    const float* arow = queue_f32 + (size_t)idx * D_K;
    bf16x8 a[8];
#pragma unroll
    for (int kc = 0; kc < 8; kc++) {
        float4 f0 = *(const float4*)(arow + kc * 32 + quad * 8);
        float4 f1 = *(const float4*)(arow + kc * 32 + quad * 8 + 4);
        u16x8 t;
        t[0] = f2bf_rn(f0.x); t[1] = f2bf_rn(f0.y); t[2] = f2bf_rn(f0.z); t[3] = f2bf_rn(f0.w);
        t[4] = f2bf_rn(f1.x); t[5] = f2bf_rn(f1.y); t[6] = f2bf_rn(f1.z); t[7] = f2bf_rn(f1.w);
        a[kc] = *(const bf16x8*)&t;
    }

    float m_run[4], l_run[4], diag[4];
#pragma unroll
    for (int r = 0; r < 4; r++) { m_run[r] = -1e30f; l_run[r] = 0.f; diag[r] = -1e30f; }

    const int tdiag = gw & 127;
    for (int tt = 0; tt < 16; tt++) {
        const int t = wave * 16 + tt;
        f32x4 acc = (f32x4){0.f, 0.f, 0.f, 0.f};
#pragma unroll
        for (int kc = 0; kc < 8; kc++) {
            bf16x8 b = *(const bf16x8*)&Bbase[(size_t)(t * 16 + l15) * D_K + kc * 32 + quad * 8];
            acc = __builtin_amdgcn_mfma_f32_16x16x32_bf16(a[kc], b, acc, 0, 0, 0);
        }
#pragma unroll
        for (int reg = 0; reg < 4; reg++) {
            float v = acc[reg] * 10.0f;              // 1/TEMPERATURE
            if (t == tdiag && l15 == quad * 4 + reg) diag[reg] = v;
            float nm = fmaxf(m_run[reg], v);
            l_run[reg] = l_run[reg] * __expf(m_run[reg] - nm) + __expf(v - nm);
            m_run[reg] = nm;
        }
    }
    // 16-lane merge within the wave
#pragma unroll
    for (int reg = 0; reg < 4; reg++) {
#pragma unroll
        for (int m = 1; m < 16; m <<= 1) {
            float om = __shfl_xor(m_run[reg], m, 16);
            float ol = __shfl_xor(l_run[reg], m, 16);
            float od = __shfl_xor(diag[reg], m, 16);
            float nm = fmaxf(m_run[reg], om);
            l_run[reg] = l_run[reg] * __expf(m_run[reg] - nm) + ol * __expf(om - nm);
            m_run[reg] = nm;
            diag[reg] = fmaxf(diag[reg], od);
        }
        if (l15 == 0) {
            sm[wave][quad * 4 + reg] = m_run[reg];
            sl[wave][quad * 4 + reg] = l_run[reg];
            sd[wave][quad * 4 + reg] = diag[reg];
        }
    }
    __syncthreads();
    // cross-wave merge + block-local reduce + single atomic into out
    if (tid < 16) {
        float M = -1e30f, L = 0.f, Dg = -1e30f;
#pragma unroll
        for (int w = 0; w < 8; w++) {
            float mw = sm[w][tid], lw = sl[w][tid], dw = sd[w][tid];
            float nM = fmaxf(M, mw);
            L = L * __expf(M - nM) + lw * __expf(mw - nM);
            M = nM;
            Dg = fmaxf(Dg, dw);
        }
        float rl = (M + __logf(L)) - Dg;
#pragma unroll
        for (int m = 1; m < 16; m <<= 1) rl += __shfl_xor(rl, m, 16);
        if (tid == 0) atomicAdd(out, rl * (1.0f / (float)B_ROWS));
    }
}

extern "C" void kernel_launch(void* const* d_in, const int* in_sizes, int n_in,
                              void* d_out, int out_size, void* d_ws, size_t ws_size,
                              hipStream_t stream) {
    const float* emb   = (const float*)d_in[0];
    const float* preds = (const float*)d_in[1];
    const float* queue = (const float*)d_in[2];

    char* w = (char*)d_ws;
    unsigned long long* amax  = (unsigned long long*)w;                     // 32 KB
    unsigned char*  emb8      = (unsigned char*)(w + (1u << 20));           // 1 MB
    unsigned short* preds_bf  = (unsigned short*)(w + (2u << 20));          // 2 MB
    unsigned char*  queue8    = (unsigned char*)(w + (4u << 20));           // 16 MB

    prep_kernel<<<dim3((EMB4 + PRED4 + QUE4) / 256), 256, 0, stream>>>(
        emb, preds, queue, emb8, preds_bf, queue8, amax, (float*)d_out);
    sim_argmax_kernel<<<dim3((B_ROWS / BM) * (Q_ROWS / (BN * NCHUNK))), 256, 0, stream>>>(
        emb8, queue8, amax);
    logits_ce_kernel<<<dim3(B_ROWS / 16), 512, 0, stream>>>(
        amax, queue, preds_bf, (float*)d_out);
}